// Round 9
// baseline (1468.154 us; speedup 1.0000x reference)
//
#include <hip/hip_runtime.h>
#include <hip/hip_bf16.h>

#define B_TOT 65536

// Round-9: two-kernel split so each phase gets codegen matched to its
// register footprint at 3 blocks/CU (52/48 KiB LDS -> 84-VGPR tier).
//   udp_mlp : S1-S4, feat written to global stash (out0|out3|out4 slices,
//             32+32+64 = 128 floats/row). acc32+weights16 ~ 70 live regs.
//   udp_dist: S5-S7, feat LDS 16K + psum 32K. S5 quarter-outer/m-inner
//             (8 rows/pass): rj16+acc16+wv8 ~ 65 live regs.
// Bit-exact: per-output-element op order identical to baseline (dot f4
// ascending xyzw; rj chains m-ascending; pairwise combines unchanged);
// feat round-trips through global as exact fp32.

// ---------------- Kernel A: MLP ----------------
__global__ __launch_bounds__(256, 2) void udp_mlp(
    const float* __restrict__ obs, const float* __restrict__ act,
    const float* __restrict__ obs2, const float* __restrict__ rew,
    const float* __restrict__ W0, const float* __restrict__ b0,
    const float* __restrict__ W1, const float* __restrict__ b1,
    const float* __restrict__ W2, const float* __restrict__ b2,
    float* __restrict__ out) {
  __shared__ __align__(16) float A_[5120];   // xs[32][160] 20KB
  __shared__ __align__(16) float Bb[8192];   // h1->h2 [32][256] 32KB
  const int t = threadIdx.x;
  const int blockRow = blockIdx.x * 32;

  float* out0 = out;                        // feat[:,0:32) stash
  float* out3 = out + (size_t)B_TOT * 34;   // feat[:,32:64) stash
  float* out4 = out + (size_t)B_TOT * 66;   // feat[:,64:128) stash

  // ---- S1: stage x = [obs | obs2-obs | act | rew] into A_ ----
  for (int i = t; i < 32 * 160; i += 256) {
    int r = i / 160, k = i - r * 160;
    int row = blockRow + r;
    float v;
    if (k < 64)        v = obs[row * 64 + k];
    else if (k < 128)  v = obs2[row * 64 + (k - 64)] - obs[row * 64 + (k - 64)];
    else if (k < 144)  v = act[row * 16 + (k - 128)];
    else if (k == 144) v = rew[row];
    else               v = 0.f;
    A_[i] = v;
  }
  __syncthreads();

  // ---- S2: layer 0 (145 -> 256). 4 neurons x 8 rows per thread ----
  {
    const int n4 = (t & 63) * 4;
    const int rbase = (t >> 6) * 8;  // wave-uniform
    float aA[8], aB[8], aC[8], aD[8];
#pragma unroll
    for (int r = 0; r < 8; ++r) { aA[r] = 0.f; aB[r] = 0.f; aC[r] = 0.f; aD[r] = 0.f; }
    const float4 bb = *(const float4*)&b0[n4];
    const float4 wt = *(const float4*)&W0[144 * 256 + n4];
    for (int k4 = 0; k4 < 144; k4 += 4) {
      const float4 w0 = *(const float4*)&W0[(k4 + 0) * 256 + n4];
      const float4 w1 = *(const float4*)&W0[(k4 + 1) * 256 + n4];
      const float4 w2 = *(const float4*)&W0[(k4 + 2) * 256 + n4];
      const float4 w3 = *(const float4*)&W0[(k4 + 3) * 256 + n4];
#pragma unroll
      for (int r = 0; r < 8; ++r) {
        const float4 xv = *(const float4*)&A_[(rbase + r) * 160 + k4];  // broadcast
        aA[r] = fmaf(xv.x, w0.x, aA[r]); aA[r] = fmaf(xv.y, w1.x, aA[r]);
        aA[r] = fmaf(xv.z, w2.x, aA[r]); aA[r] = fmaf(xv.w, w3.x, aA[r]);
        aB[r] = fmaf(xv.x, w0.y, aB[r]); aB[r] = fmaf(xv.y, w1.y, aB[r]);
        aB[r] = fmaf(xv.z, w2.y, aB[r]); aB[r] = fmaf(xv.w, w3.y, aB[r]);
        aC[r] = fmaf(xv.x, w0.z, aC[r]); aC[r] = fmaf(xv.y, w1.z, aC[r]);
        aC[r] = fmaf(xv.z, w2.z, aC[r]); aC[r] = fmaf(xv.w, w3.z, aC[r]);
        aD[r] = fmaf(xv.x, w0.w, aD[r]); aD[r] = fmaf(xv.y, w1.w, aD[r]);
        aD[r] = fmaf(xv.z, w2.w, aD[r]); aD[r] = fmaf(xv.w, w3.w, aD[r]);
      }
    }
#pragma unroll
    for (int r = 0; r < 8; ++r) {
      const float xt = A_[(rbase + r) * 160 + 144];
      aA[r] = fmaf(xt, wt.x, aA[r]); aB[r] = fmaf(xt, wt.y, aB[r]);
      aC[r] = fmaf(xt, wt.z, aC[r]); aD[r] = fmaf(xt, wt.w, aD[r]);
    }
#pragma unroll
    for (int r = 0; r < 8; ++r) {
      float4 v;
      v.x = aA[r] + bb.x; v.x = v.x > 0.f ? v.x : 0.01f * v.x;
      v.y = aB[r] + bb.y; v.y = v.y > 0.f ? v.y : 0.01f * v.y;
      v.z = aC[r] + bb.z; v.z = v.z > 0.f ? v.z : 0.01f * v.z;
      v.w = aD[r] + bb.w; v.w = v.w > 0.f ? v.w : 0.01f * v.w;
      *(float4*)&Bb[(rbase + r) * 256 + n4] = v;  // h1
    }
  }
  __syncthreads();

  // ---- S3: layer 1 (256 -> 256). h2 overwrites h1 (barrier before write) ----
  {
    const int n4 = (t & 63) * 4;
    const int rbase = (t >> 6) * 8;
    float aA[8], aB[8], aC[8], aD[8];
#pragma unroll
    for (int r = 0; r < 8; ++r) { aA[r] = 0.f; aB[r] = 0.f; aC[r] = 0.f; aD[r] = 0.f; }
    const float4 bb = *(const float4*)&b1[n4];
    for (int k4 = 0; k4 < 256; k4 += 4) {
      const float4 w0 = *(const float4*)&W1[(k4 + 0) * 256 + n4];
      const float4 w1 = *(const float4*)&W1[(k4 + 1) * 256 + n4];
      const float4 w2 = *(const float4*)&W1[(k4 + 2) * 256 + n4];
      const float4 w3 = *(const float4*)&W1[(k4 + 3) * 256 + n4];
#pragma unroll
      for (int r = 0; r < 8; ++r) {
        const float4 xv = *(const float4*)&Bb[(rbase + r) * 256 + k4];  // broadcast
        aA[r] = fmaf(xv.x, w0.x, aA[r]); aA[r] = fmaf(xv.y, w1.x, aA[r]);
        aA[r] = fmaf(xv.z, w2.x, aA[r]); aA[r] = fmaf(xv.w, w3.x, aA[r]);
        aB[r] = fmaf(xv.x, w0.y, aB[r]); aB[r] = fmaf(xv.y, w1.y, aB[r]);
        aB[r] = fmaf(xv.z, w2.y, aB[r]); aB[r] = fmaf(xv.w, w3.y, aB[r]);
        aC[r] = fmaf(xv.x, w0.z, aC[r]); aC[r] = fmaf(xv.y, w1.z, aC[r]);
        aC[r] = fmaf(xv.z, w2.z, aC[r]); aC[r] = fmaf(xv.w, w3.z, aC[r]);
        aD[r] = fmaf(xv.x, w0.w, aD[r]); aD[r] = fmaf(xv.y, w1.w, aD[r]);
        aD[r] = fmaf(xv.z, w2.w, aD[r]); aD[r] = fmaf(xv.w, w3.w, aD[r]);
      }
    }
    __syncthreads();  // all h1 reads done before any h2 write
#pragma unroll
    for (int r = 0; r < 8; ++r) {
      float4 v;
      v.x = aA[r] + bb.x; v.x = v.x > 0.f ? v.x : 0.01f * v.x;
      v.y = aB[r] + bb.y; v.y = v.y > 0.f ? v.y : 0.01f * v.y;
      v.z = aC[r] + bb.z; v.z = v.z > 0.f ? v.z : 0.01f * v.z;
      v.w = aD[r] + bb.w; v.w = v.w > 0.f ? v.w : 0.01f * v.w;
      *(float4*)&Bb[(rbase + r) * 256 + n4] = v;  // h2 (in place)
    }
  }
  __syncthreads();

  // ---- S4: layer 2 (256 -> 128). 4 neurons x 4 rows; feat -> global stash ----
  {
    const int n4 = (t & 31) * 4;
    const int rbase = (t >> 5) * 4;
    float aA[4], aB[4], aC[4], aD[4];
#pragma unroll
    for (int r = 0; r < 4; ++r) { aA[r] = 0.f; aB[r] = 0.f; aC[r] = 0.f; aD[r] = 0.f; }
    const float4 bb = *(const float4*)&b2[n4];
    for (int k4 = 0; k4 < 256; k4 += 4) {
      const float4 w0 = *(const float4*)&W2[(k4 + 0) * 128 + n4];
      const float4 w1 = *(const float4*)&W2[(k4 + 1) * 128 + n4];
      const float4 w2 = *(const float4*)&W2[(k4 + 2) * 128 + n4];
      const float4 w3 = *(const float4*)&W2[(k4 + 3) * 128 + n4];
#pragma unroll
      for (int r = 0; r < 4; ++r) {
        const float4 xv = *(const float4*)&Bb[(rbase + r) * 256 + k4];
        aA[r] = fmaf(xv.x, w0.x, aA[r]); aA[r] = fmaf(xv.y, w1.x, aA[r]);
        aA[r] = fmaf(xv.z, w2.x, aA[r]); aA[r] = fmaf(xv.w, w3.x, aA[r]);
        aB[r] = fmaf(xv.x, w0.y, aB[r]); aB[r] = fmaf(xv.y, w1.y, aB[r]);
        aB[r] = fmaf(xv.z, w2.y, aB[r]); aB[r] = fmaf(xv.w, w3.y, aB[r]);
        aC[r] = fmaf(xv.x, w0.z, aC[r]); aC[r] = fmaf(xv.y, w1.z, aC[r]);
        aC[r] = fmaf(xv.z, w2.z, aC[r]); aC[r] = fmaf(xv.w, w3.z, aC[r]);
        aD[r] = fmaf(xv.x, w0.w, aD[r]); aD[r] = fmaf(xv.y, w1.w, aD[r]);
        aD[r] = fmaf(xv.z, w2.w, aD[r]); aD[r] = fmaf(xv.w, w3.w, aD[r]);
      }
    }
#pragma unroll
    for (int r = 0; r < 4; ++r) {
      float4 v;
      v.x = aA[r] + bb.x; v.x = v.x > 0.f ? v.x : 0.01f * v.x;
      v.y = aB[r] + bb.y; v.y = v.y > 0.f ? v.y : 0.01f * v.y;
      v.z = aC[r] + bb.z; v.z = v.z > 0.f ? v.z : 0.01f * v.z;
      v.w = aD[r] + bb.w; v.w = v.w > 0.f ? v.w : 0.01f * v.w;
      const size_t row = (size_t)blockRow + rbase + r;
      if (n4 < 32)      *(float4*)&out0[row * 32 + n4] = v;
      else if (n4 < 64) *(float4*)&out3[row * 32 + (n4 - 32)] = v;
      else              *(float4*)&out4[row * 64 + (n4 - 64)] = v;
    }
  }
}

// ---------------- Kernel B: projection + distance + outputs ----------------
__global__ __launch_bounds__(256, 2) void udp_dist(
    const float* __restrict__ Wp, const float* __restrict__ emb,
    const float* __restrict__ sigma, float* __restrict__ out) {
  __shared__ __align__(16) float A_[8192];   // psum[32][4][64] swizzled, 32KB
  __shared__ __align__(16) float Bb[4096];   // feat[32][128] 16KB
  const int t = threadIdx.x;
  const int blockRow = blockIdx.x * 32;

  float* out0 = out;                        // chosen_embedding (B,32) [feat stash 0:32]
  float* out1 = out + (size_t)B_TOT * 32;   // chosen_dist (B,1)
  float* out2 = out + (size_t)B_TOT * 33;   // idx (B,1) as float
  float* out3 = out + (size_t)B_TOT * 34;   // chosen_mean (B,32) [feat stash 32:64]
  float* out4 = out + (size_t)B_TOT * 66;   // distance (B,64)  [feat stash 64:128]

  // ---- F1: load feat stash -> LDS ----
  for (int i = t; i < 1024; i += 256) {   // 1024 float4s = 32*128
    const int r = i >> 5, c4 = (i & 31) * 4;
    const size_t row = (size_t)blockRow + r;
    float4 v;
    if (c4 < 32)      v = *(const float4*)&out0[row * 32 + c4];
    else if (c4 < 64) v = *(const float4*)&out3[row * 32 + (c4 - 32)];
    else              v = *(const float4*)&out4[row * 64 + (c4 - 64)];
    *(float4*)&Bb[r * 128 + c4] = v;
  }
  __syncthreads();

  // ---- S5: projection + diff^2 partials, quarter-outer / m-inner ----
  // thread = (env n = t&63, partial p = t>>6). Owns numpy chains j=2p,2p+1.
  // Per (thread,e,row): dot f4-ascending xyzw; rj chains m-ascending ->
  // bit-exact vs baseline. 8 rows per quarter keeps ~65 live floats.
  {
    const int n = t & 63, pp = t >> 6;
    const float* wb = Wp + (size_t)n * 32 * 128;
    const float* eb = emb + n * 32;
#pragma unroll 1
    for (int q = 0; q < 4; ++q) {
      const int rbase = q * 8;
      float rj0[8], rj1[8];
#pragma unroll
      for (int r = 0; r < 8; ++r) { rj0[r] = 0.f; rj1[r] = 0.f; }
#pragma unroll 1
      for (int m = 0; m < 4; ++m) {
        const int e0 = 2 * pp + 8 * m;
        const int e1 = e0 + 1;
        const float* w0p = wb + e0 * 128;
        const float* w1p = wb + e1 * 128;
        const float em0 = eb[e0], em1 = eb[e1];
        float acc0[8], acc1[8];
#pragma unroll
        for (int r = 0; r < 8; ++r) { acc0[r] = 0.f; acc1[r] = 0.f; }
        for (int f4 = 0; f4 < 128; f4 += 4) {
          const float4 wv0 = *(const float4*)(w0p + f4);
          const float4 wv1 = *(const float4*)(w1p + f4);
#pragma unroll
          for (int r = 0; r < 8; ++r) {
            const float4 fv = *(const float4*)&Bb[(rbase + r) * 128 + f4];  // broadcast
            acc0[r] = fmaf(fv.x, wv0.x, acc0[r]);
            acc0[r] = fmaf(fv.y, wv0.y, acc0[r]);
            acc0[r] = fmaf(fv.z, wv0.z, acc0[r]);
            acc0[r] = fmaf(fv.w, wv0.w, acc0[r]);
            acc1[r] = fmaf(fv.x, wv1.x, acc1[r]);
            acc1[r] = fmaf(fv.y, wv1.y, acc1[r]);
            acc1[r] = fmaf(fv.z, wv1.z, acc1[r]);
            acc1[r] = fmaf(fv.w, wv1.w, acc1[r]);
          }
        }
#pragma unroll
        for (int r = 0; r < 8; ++r) {
          float d0 = acc0[r] - em0;
          rj0[r] = fmaf(d0, d0, rj0[r]);
          float d1 = acc1[r] - em1;
          rj1[r] = fmaf(d1, d1, rj1[r]);
        }
      }
      // psum[r][pp][(n+r)&63]: write 2-way (free), S6 read conflict-free
#pragma unroll
      for (int r = 0; r < 8; ++r) {
        const int gr = rbase + r;
        A_[gr * 256 + pp * 64 + ((n + gr) & 63)] = rj0[r] + rj1[r];
      }
    }
  }
  __syncthreads();

  // ---- S6: distance + argmin per row (threads 0..31) ----
  // dist overwrites psum[r][0][nr] (same-thread same-iter read first);
  // idx stored at [r][1][0]-slot after loop (all reads done).
  if (t < 32) {
    const int r = t;
    const size_t row = (size_t)blockRow + r;
    float best = 1e30f;
    int bi = 0;
    for (int n = 0; n < 64; ++n) {
      const int nr = (n + r) & 63;
      const float p0 = A_[r * 256 + 0 * 64 + nr];
      const float p1 = A_[r * 256 + 1 * 64 + nr];
      const float p2 = A_[r * 256 + 2 * 64 + nr];
      const float p3 = A_[r * 256 + 3 * 64 + nr];
      float s = (p0 + p1) + (p2 + p3);  // numpy pairwise combine
      float mean = s / 32.0f;           // exact (pow2)
      float sg = sigma[n];
      float den = 2.0f * sg * sg;
      float dist = expf((-mean) / den);
      A_[r * 256 + nr] = dist;          // swizzled dist store
      if (dist < best) { best = dist; bi = n; }  // np.argmin first-min
    }
    A_[r * 256 + 64] = (float)bi;
    out1[row] = best;
    out2[row] = (float)bi;
  }
  __syncthreads();

  // ---- S7a: distance matrix out (undo swizzle; overwrites feat stash hi) ----
  for (int i = t; i < 32 * 64; i += 256) {
    int r = i >> 6, n = i & 63;
    out4[(size_t)(blockRow + r) * 64 + n] = A_[r * 256 + ((n + r) & 63)];
  }
  // ---- S7b: chosen embedding (recompute f2e[idx]) + chosen mean ----
  for (int i = t; i < 32 * 32; i += 256) {
    int r = i >> 5, e = i & 31;
    int bi = (int)A_[r * 256 + 64];
    const float* wrow = Wp + (bi * 32 + e) * 128;
    float acc = 0.f;
    for (int f4 = 0; f4 < 128; f4 += 4) {
      const float4 wv = *(const float4*)(wrow + f4);
      const float4 fv = *(const float4*)&Bb[r * 128 + f4];
      acc = fmaf(fv.x, wv.x, acc);
      acc = fmaf(fv.y, wv.y, acc);
      acc = fmaf(fv.z, wv.z, acc);
      acc = fmaf(fv.w, wv.w, acc);
    }
    size_t row = (size_t)blockRow + r;
    out0[row * 32 + e] = acc;
    out3[row * 32 + e] = emb[bi * 32 + e];
  }
}

extern "C" void kernel_launch(void* const* d_in, const int* in_sizes, int n_in,
                              void* d_out, int out_size, void* d_ws, size_t ws_size,
                              hipStream_t stream) {
  const float* obs   = (const float*)d_in[0];
  const float* act   = (const float*)d_in[1];
  const float* obs2  = (const float*)d_in[2];
  const float* rew   = (const float*)d_in[3];
  const float* W0    = (const float*)d_in[4];
  const float* b0    = (const float*)d_in[5];
  const float* W1    = (const float*)d_in[6];
  const float* b1    = (const float*)d_in[7];
  const float* W2    = (const float*)d_in[8];
  const float* b2    = (const float*)d_in[9];
  const float* Wp    = (const float*)d_in[10];
  const float* e_emb = (const float*)d_in[11];
  const float* sigma = (const float*)d_in[12];

  udp_mlp<<<dim3(B_TOT / 32), dim3(256), 0, stream>>>(
      obs, act, obs2, rew, W0, b0, W1, b1, W2, b2, (float*)d_out);
  udp_dist<<<dim3(B_TOT / 32), dim3(256), 0, stream>>>(
      Wp, e_emb, sigma, (float*)d_out);
}